// Round 6
// baseline (772.687 us; speedup 1.0000x reference)
//
#include <hip/hip_runtime.h>
#include <cstdint>
#include <cstddef>

#define SEQ      4096
#define DIMIN    2048
#define HID      4096
#define STATE    128
#define HEADS    64
#define HEAD_DIM 64
#define CONV_DIM 4352   // HID + 2*STATE
#define D_IN     8512
#define WROWS    8576   // in_proj rows padded to 67*128
#define XBCD_N   4480   // xBC+dt width: 4416 padded (8576-4096)
#define CHUNK    256
#define NCHUNK   16

typedef __attribute__((ext_vector_type(8))) short short8;
typedef __attribute__((ext_vector_type(4))) float floatx4;
typedef __attribute__((ext_vector_type(4))) unsigned int uintx4;

#define AS1 __attribute__((address_space(1)))
#define AS3 __attribute__((address_space(3)))
__device__ __forceinline__ void gload_lds16(const void* g, void* l) {
    __builtin_amdgcn_global_load_lds((const AS1 unsigned int*)g, (AS3 unsigned int*)l, 16, 0, 0);
}

__device__ __forceinline__ unsigned short f2bf(float f) {
    union { float f; unsigned int u; } v; v.f = f;
    unsigned int r = v.u + 0x7FFFu + ((v.u >> 16) & 1u);
    return (unsigned short)(r >> 16);
}
__device__ __forceinline__ float bf2f(unsigned short u) {
    union { unsigned int u; float f; } v; v.u = ((unsigned int)u) << 16;
    return v.f;
}

// ---------------- fp32 -> bf16 convert (with zero tail padding) ----------------
__global__ void k_convert(const float* __restrict__ src, unsigned short* __restrict__ dst,
                          long n, long nsrc) {
    long i = (long)blockIdx.x * blockDim.x + threadIdx.x;
    if (i >= n) return;
    float v = (i < nsrc) ? src[i] : 0.f;
    dst[i] = f2bf(v);
}

// ---------------- bf16 MFMA GEMM core (m97-style: global_load_lds + XOR swizzle) ----------------
#define BM 128
#define BN 128
#define BK 64

// Shared K-loop; MODE 0: fp32 single-dest (GEMM2). k_gemm_dual below: merged GEMM1.
__global__ __launch_bounds__(256) void k_gemm_f32(
    const unsigned short* __restrict__ A, const unsigned short* __restrict__ B,
    float* __restrict__ Cout, int K, int ldc)
{
    __shared__ __attribute__((aligned(16))) unsigned short As[BM * BK];
    __shared__ __attribute__((aligned(16))) unsigned short Bs[BN * BK];
    const int tid = threadIdx.x;
    const int GN = 8;
    const int nbx = gridDim.x, nby = gridDim.y;
    int flat = blockIdx.y * nbx + blockIdx.x;
    int group = flat / (GN * nby);
    int gw = min(GN, nbx - group * GN);
    int rem = flat - group * (GN * nby);
    int bn = group * GN + rem % gw;
    int bm = rem / gw;

    const int wid = tid >> 6, lane = tid & 63;
    const int wm = (wid >> 1) * 64, wn = (wid & 1) * 64;
    const int lrow = lane & 15;
    const int gk = lane >> 4;
    const int srow = lane >> 3;
    const int sgrp = (lane & 7) ^ (lane >> 3);

    floatx4 acc[4][4];
#pragma unroll
    for (int i = 0; i < 4; ++i)
#pragma unroll
        for (int j = 0; j < 4; ++j) acc[i][j] = (floatx4){0.f, 0.f, 0.f, 0.f};

    const long a_base = (long)bm * BM * K;
    const long b_base = (long)bn * BN * K;

    for (int k0 = 0; k0 < K; k0 += BK) {
        const unsigned short* Ak = A + a_base + k0;
        const unsigned short* Bk = B + b_base + k0;
#pragma unroll
        for (int i = 0; i < 4; ++i) {
            int rbase = wid * 32 + i * 8;
            gload_lds16(Ak + (long)(rbase + srow) * K + sgrp * 8, &As[rbase * BK]);
            gload_lds16(Bk + (long)(rbase + srow) * K + sgrp * 8, &Bs[rbase * BK]);
        }
        __syncthreads();
#pragma unroll
        for (int kk = 0; kk < BK; kk += 32) {
            const int slot8 = (((kk >> 3) + gk) ^ (lrow & 7)) * 8;
            short8 af[4], bfr[4];
#pragma unroll
            for (int i = 0; i < 4; ++i)
                af[i] = *(const short8*)&As[(wm + i * 16 + lrow) * BK + slot8];
#pragma unroll
            for (int j = 0; j < 4; ++j)
                bfr[j] = *(const short8*)&Bs[(wn + j * 16 + lrow) * BK + slot8];
#pragma unroll
            for (int i = 0; i < 4; ++i)
#pragma unroll
                for (int j = 0; j < 4; ++j)
                    acc[i][j] = __builtin_amdgcn_mfma_f32_16x16x32_bf16(af[i], bfr[j], acc[i][j], 0, 0, 0);
        }
        __syncthreads();
    }
    const int rcol = lane & 15;
    const int rrow = (lane >> 4) * 4;
#pragma unroll
    for (int i = 0; i < 4; ++i)
#pragma unroll
        for (int j = 0; j < 4; ++j) {
            int col = bn * BN + wn + j * 16 + rcol;
#pragma unroll
            for (int r = 0; r < 4; ++r) {
                int row = bm * BM + wm + i * 16 + rrow + r;
                Cout[(long)row * ldc + col] = acc[i][j][r];
            }
        }
}

// Merged GEMM1: N = WROWS(8576). cols<4096 -> z bf16 (d_out); cols>=4096 -> xbcd bf16
// (col-4096, stride 4480) + fp32 dt side-channel for cols [8448,8512).
__global__ __launch_bounds__(256) void k_gemm_dual(
    const unsigned short* __restrict__ A, const unsigned short* __restrict__ B,
    unsigned short* __restrict__ z, unsigned short* __restrict__ xbcd,
    float* __restrict__ dtraw, int K)
{
    __shared__ __attribute__((aligned(16))) unsigned short As[BM * BK];
    __shared__ __attribute__((aligned(16))) unsigned short Bs[BN * BK];
    const int tid = threadIdx.x;
    const int GN = 8;
    const int nbx = gridDim.x, nby = gridDim.y;
    int flat = blockIdx.y * nbx + blockIdx.x;
    int group = flat / (GN * nby);
    int gw = min(GN, nbx - group * GN);
    int rem = flat - group * (GN * nby);
    int bn = group * GN + rem % gw;
    int bm = rem / gw;

    const int wid = tid >> 6, lane = tid & 63;
    const int wm = (wid >> 1) * 64, wn = (wid & 1) * 64;
    const int lrow = lane & 15;
    const int gk = lane >> 4;
    const int srow = lane >> 3;
    const int sgrp = (lane & 7) ^ (lane >> 3);

    floatx4 acc[4][4];
#pragma unroll
    for (int i = 0; i < 4; ++i)
#pragma unroll
        for (int j = 0; j < 4; ++j) acc[i][j] = (floatx4){0.f, 0.f, 0.f, 0.f};

    const long a_base = (long)bm * BM * K;
    const long b_base = (long)bn * BN * K;

    for (int k0 = 0; k0 < K; k0 += BK) {
        const unsigned short* Ak = A + a_base + k0;
        const unsigned short* Bk = B + b_base + k0;
#pragma unroll
        for (int i = 0; i < 4; ++i) {
            int rbase = wid * 32 + i * 8;
            gload_lds16(Ak + (long)(rbase + srow) * K + sgrp * 8, &As[rbase * BK]);
            gload_lds16(Bk + (long)(rbase + srow) * K + sgrp * 8, &Bs[rbase * BK]);
        }
        __syncthreads();
#pragma unroll
        for (int kk = 0; kk < BK; kk += 32) {
            const int slot8 = (((kk >> 3) + gk) ^ (lrow & 7)) * 8;
            short8 af[4], bfr[4];
#pragma unroll
            for (int i = 0; i < 4; ++i)
                af[i] = *(const short8*)&As[(wm + i * 16 + lrow) * BK + slot8];
#pragma unroll
            for (int j = 0; j < 4; ++j)
                bfr[j] = *(const short8*)&Bs[(wn + j * 16 + lrow) * BK + slot8];
#pragma unroll
            for (int i = 0; i < 4; ++i)
#pragma unroll
                for (int j = 0; j < 4; ++j)
                    acc[i][j] = __builtin_amdgcn_mfma_f32_16x16x32_bf16(af[i], bfr[j], acc[i][j], 0, 0, 0);
        }
        __syncthreads();
    }
    const int rcol = lane & 15;
    const int rrow = (lane >> 4) * 4;
    if (bn < HID / BN) {   // z destination (block-uniform)
#pragma unroll
        for (int i = 0; i < 4; ++i)
#pragma unroll
            for (int j = 0; j < 4; ++j) {
                int col = bn * BN + wn + j * 16 + rcol;
#pragma unroll
                for (int r = 0; r < 4; ++r) {
                    int row = bm * BM + wm + i * 16 + rrow + r;
                    z[(long)row * HID + col] = f2bf(acc[i][j][r]);
                }
            }
    } else {               // xBC+dt destination
#pragma unroll
        for (int i = 0; i < 4; ++i)
#pragma unroll
            for (int j = 0; j < 4; ++j) {
                int col = bn * BN + wn + j * 16 + rcol;
                int c2 = col - HID;
#pragma unroll
                for (int r = 0; r < 4; ++r) {
                    int row = bm * BM + wm + i * 16 + rrow + r;
                    float v = acc[i][j][r];
                    xbcd[(long)row * XBCD_N + c2] = f2bf(v);
                    if (col >= 8448 && col < 8512)
                        dtraw[(long)row * 64 + (col - 8448)] = v;
                }
            }
    }
}

// ---------------- causal conv1d (k=4) + SiLU, bf16 in/out ----------------
__global__ void k_conv(const unsigned short* __restrict__ xbcd, const float* __restrict__ convw,
                       unsigned short* __restrict__ xc) {
    long i = (long)blockIdx.x * 256 + threadIdx.x;
    if (i >= (long)SEQ * CONV_DIM) return;
    int c = (int)(i % CONV_DIM);
    int s = (int)(i / CONV_DIM);
    float w0 = convw[c * 4 + 0], w1 = convw[c * 4 + 1];
    float w2 = convw[c * 4 + 2], w3 = convw[c * 4 + 3];
    float acc = bf2f(xbcd[(long)s * XBCD_N + c]) * w3;
    if (s >= 1) acc += bf2f(xbcd[(long)(s - 1) * XBCD_N + c]) * w2;
    if (s >= 2) acc += bf2f(xbcd[(long)(s - 2) * XBCD_N + c]) * w1;
    if (s >= 3) acc += bf2f(xbcd[(long)(s - 3) * XBCD_N + c]) * w0;
    float sl = acc / (1.f + __expf(-acc));
    xc[i] = f2bf(sl);
}

// ---------------- dt = softplus(dtraw+bias), dA = dt*A, per-chunk inclusive cumsum ----------------
__global__ __launch_bounds__(256) void k_dt(const float* __restrict__ dtraw,
        const float* __restrict__ dt_bias, const float* __restrict__ A_log,
        float* __restrict__ dtv, float* __restrict__ dAc, float* __restrict__ dAlast)
{
    int c = blockIdx.x, h = blockIdx.y;
    int l = threadIdx.x;
    __shared__ float sh[CHUNK];
    float v = dtraw[(long)(c * CHUNK + l) * 64 + h] + dt_bias[h];
    float dt = (v > 20.f) ? v : log1pf(__expf(v));
    float Ah = -__expf(A_log[h]);
    float dA = dt * Ah;
    sh[l] = dA;
    __syncthreads();
    float x = dA;
#pragma unroll
    for (int off = 1; off < CHUNK; off <<= 1) {
        float t = (l >= off) ? sh[l - off] : 0.f;
        __syncthreads();
        x += t;
        sh[l] = x;
        __syncthreads();
    }
    dtv[(long)(c * CHUNK + l) * HEADS + h] = dt;
    dAc[(long)(c * CHUNK + l) * HEADS + h] = x;
    if (l == CHUNK - 1) dAlast[c * HEADS + h] = x;
}

// ---------------- G[c][l][s] = C[l] . B[s] ----------------
__global__ __launch_bounds__(256) void k_G(const unsigned short* __restrict__ xc, float* __restrict__ G) {
    int c = blockIdx.x, l = blockIdx.y;
    int s = threadIdx.x;
    __shared__ float Csh[STATE];
    if (s < STATE) Csh[s] = bf2f(xc[(long)(c * CHUNK + l) * CONV_DIM + HID + STATE + s]);
    __syncthreads();
    const unsigned short* Brow = xc + (long)(c * CHUNK + s) * CONV_DIM + HID;
    float acc = 0.f;
#pragma unroll
    for (int n = 0; n < STATE; n += 8) {
        short8 b8 = *(const short8*)&Brow[n];
#pragma unroll
        for (int j = 0; j < 8; ++j)
            acc += Csh[n + j] * bf2f((unsigned short)b8[j]);
    }
    G[((long)c * CHUNK + l) * CHUNK + s] = acc;
}

// ---------------- states (MFMA): states[c,h,p,n] = sum_l xds^T[p,l] * B^T[n,l] ----------------
// xds[l,p] = x[l,p]*exp(dAlast-dAc[l])*dt[l]. Both operands staged transposed [out][l]
// bf16 in LDS (stride 72, same balanced-bank property as k_gemm). k-blocked by 64.
// Round-5 version was scalar VALU (8192 FMA/thread) with per-element B loads.
#define KST 72
__global__ __launch_bounds__(256) void k_states(
    const unsigned short* __restrict__ xc, const float* __restrict__ dtv,
    const float* __restrict__ dAc, const float* __restrict__ dAlast,
    float* __restrict__ states)
{
    __shared__ __attribute__((aligned(16))) unsigned short BT[STATE * KST];
    __shared__ __attribute__((aligned(16))) unsigned short xdsT[64 * KST];
    __shared__ float dA_sh[CHUNK], dt_sh[CHUNK];
    const int c = blockIdx.x, h = blockIdx.y;
    const int t = threadIdx.x;
    const int w = t >> 6, lane = t & 63;
    const long base_s = (long)c * CHUNK;
    dA_sh[t] = dAc[(base_s + t) * HEADS + h];
    dt_sh[t] = dtv[(base_s + t) * HEADS + h];
    __syncthreads();
    const float dAl = dAlast[c * HEADS + h];
    const int lrow = lane & 15;
    const int kgrp = (lane >> 4) * 8;

    floatx4 acc[4][2];
#pragma unroll
    for (int i = 0; i < 4; ++i)
#pragma unroll
        for (int j = 0; j < 2; ++j) acc[i][j] = (floatx4){0.f, 0.f, 0.f, 0.f};

    for (int lb = 0; lb < 4; ++lb) {
        const long row0 = base_s + lb * 64;
        // BT[n][l] from B[l][n] (coalesced reads, 8-way b16 LDS writes - minor)
#pragma unroll
        for (int i = 0; i < 32; ++i) {
            int e = t + i * 256;
            int n = e & 127, l = e >> 7;
            BT[n * KST + l] = xc[(row0 + l) * CONV_DIM + HID + n];
        }
        // xdsT[p][l]
#pragma unroll
        for (int i = 0; i < 16; ++i) {
            int e = t + i * 256;
            int p = e & 63, l = e >> 6;
            float ds = __expf(dAl - dA_sh[lb * 64 + l]) * dt_sh[lb * 64 + l];
            xdsT[p * KST + l] = f2bf(bf2f(xc[(row0 + l) * CONV_DIM + h * HEAD_DIM + p]) * ds);
        }
        __syncthreads();
#pragma unroll
        for (int kk = 0; kk < 64; kk += 32) {
            short8 af[4], bfr[2];
#pragma unroll
            for (int i = 0; i < 4; ++i)
                af[i] = *(const short8*)&xdsT[(i * 16 + lrow) * KST + kk + kgrp];
#pragma unroll
            for (int j = 0; j < 2; ++j)
                bfr[j] = *(const short8*)&BT[(w * 32 + j * 16 + lrow) * KST + kk + kgrp];
#pragma unroll
            for (int i = 0; i < 4; ++i)
#pragma unroll
                for (int j = 0; j < 2; ++j)
                    acc[i][j] = __builtin_amdgcn_mfma_f32_16x16x32_bf16(af[i], bfr[j], acc[i][j], 0, 0, 0);
        }
        __syncthreads();
    }
    float* Sb = states + (long)(c * HEADS + h) * HEAD_DIM * STATE;
    const int rrow = (lane >> 4) * 4;
#pragma unroll
    for (int i = 0; i < 4; ++i)
#pragma unroll
        for (int j = 0; j < 2; ++j) {
            int n = w * 32 + j * 16 + lrow;
#pragma unroll
            for (int r = 0; r < 4; ++r) {
                int p = i * 16 + rrow + r;
                Sb[p * STATE + n] = acc[i][j][r];
            }
        }
}

// ---------------- sequential chunk-state scan (in place: states[c] := prev state) ----------------
__global__ void k_scan(float* __restrict__ states, const float* __restrict__ dAlast) {
    int t = blockIdx.x * 256 + threadIdx.x;
    if (t >= HEADS * HEAD_DIM * STATE) return;
    int h = t >> 13;
    const long stride = (long)HEADS * HEAD_DIM * STATE;
    float carry = 0.f;
    for (int c = 0; c < NCHUNK; ++c) {
        float s = states[c * stride + t];
        float dec = __expf(dAlast[c * HEADS + h]);
        states[c * stride + t] = carry;
        carry = carry * dec + s;
    }
}

// ---------------- y = y_off + y_diag + D*x (MFMA version), bf16 out ----------------
#define XDTS 264   // row stride: 528 B -> 16B-aligned rows, balanced banks
#define PVS  136
__global__ __launch_bounds__(256, 3) void k_ssd_y(
    const unsigned short* __restrict__ xc, const float* __restrict__ G,
    const float* __restrict__ dtv, const float* __restrict__ dAc,
    const float* __restrict__ prev, const float* __restrict__ Dp,
    unsigned short* __restrict__ y)
{
    __shared__ __attribute__((aligned(16))) unsigned short xdtT[64 * XDTS];
    __shared__ __attribute__((aligned(16))) unsigned short pvB[64 * PVS];
    __shared__ float dA_sh[CHUNK];
    __shared__ float dt_sh[CHUNK];
    const int c = blockIdx.x, h = blockIdx.y;
    const int t = threadIdx.x;
    const int w = t >> 6, lane = t & 63;
    const long base_s = (long)c * CHUNK;

    dA_sh[t] = dAc[(base_s + t) * HEADS + h];
    dt_sh[t] = dtv[(base_s + t) * HEADS + h];
    __syncthreads();

    {
        const float* Pb = prev + (long)(c * HEADS + h) * HEAD_DIM * STATE;
#pragma unroll
        for (int i = 0; i < 32; ++i) {
            int e = t + i * 256;
            int p = e >> 7, n = e & 127;
            pvB[p * PVS + n] = f2bf(Pb[e]);
        }
    }
#pragma unroll
    for (int i = 0; i < 64; ++i) {
        int e = t + i * 256;
        int p = e & 63, s = e >> 6;
        float v = bf2f(xc[(base_s + s) * CONV_DIM + h * HEAD_DIM + p]) * dt_sh[s];
        xdtT[p * XDTS + s] = f2bf(v);
    }
    __syncthreads();

    floatx4 acc[4][4];
#pragma unroll
    for (int i = 0; i < 4; ++i)
#pragma unroll
        for (int j = 0; j < 4; ++j) acc[i][j] = (floatx4){0.f, 0.f, 0.f, 0.f};

    const int lrow = lane & 15;
    const int kgrp = (lane >> 4) * 8;
    float myA[4], eAl[4];
#pragma unroll
    for (int i = 0; i < 4; ++i) {
        int l = w * 64 + i * 16 + lrow;
        myA[i] = dA_sh[l];
        eAl[i] = __expf(myA[i]);
    }

    // ---- off term ----
    for (int k0 = 0; k0 < STATE; k0 += 32) {
        short8 af[4], bfr[4];
#pragma unroll
        for (int i = 0; i < 4; ++i) {
            int l = w * 64 + i * 16 + lrow;
            union { short8 v; unsigned short u[8]; } r, o;
            r.v = *(const short8*)&xc[(base_s + l) * CONV_DIM + (HID + STATE) + k0 + kgrp];
#pragma unroll
            for (int j = 0; j < 8; ++j) o.u[j] = f2bf(bf2f(r.u[j]) * eAl[i]);
            af[i] = o.v;
        }
#pragma unroll
        for (int j = 0; j < 4; ++j)
            bfr[j] = *(const short8*)&pvB[(j * 16 + lrow) * PVS + k0 + kgrp];
#pragma unroll
        for (int i = 0; i < 4; ++i)
#pragma unroll
            for (int j = 0; j < 4; ++j)
                acc[i][j] = __builtin_amdgcn_mfma_f32_16x16x32_bf16(af[i], bfr[j], acc[i][j], 0, 0, 0);
    }

    // ---- diag term ----
    for (int k0 = 0; k0 < (w + 1) * 64; k0 += 32) {
        short8 af[4], bfr[4];
#pragma unroll
        for (int i = 0; i < 4; ++i) {
            int l = w * 64 + i * 16 + lrow;
            const float* Gp = G + (base_s + l) * (long)CHUNK + k0 + kgrp;
            float4 g0 = *(const float4*)Gp;
            float4 g1 = *(const float4*)(Gp + 4);
            float ga[8] = {g0.x, g0.y, g0.z, g0.w, g1.x, g1.y, g1.z, g1.w};
            union { short8 v; unsigned short u[8]; } o;
#pragma unroll
            for (int j = 0; j < 8; ++j) {
                int s = k0 + kgrp + j;
                float e = __expf(fminf(myA[i] - dA_sh[s], 0.f));
                float m = (s <= l) ? ga[j] * e : 0.f;
                o.u[j] = f2bf(m);
            }
            af[i] = o.v;
        }
#pragma unroll
        for (int j = 0; j < 4; ++j)
            bfr[j] = *(const short8*)&xdtT[(j * 16 + lrow) * XDTS + k0 + kgrp];
#pragma unroll
        for (int i = 0; i < 4; ++i)
#pragma unroll
            for (int j = 0; j < 4; ++j)
                acc[i][j] = __builtin_amdgcn_mfma_f32_16x16x32_bf16(af[i], bfr[j], acc[i][j], 0, 0, 0);
    }

    // ---- epilogue ----
    const float Dh = Dp[h];
    const int rrow = (lane >> 4) * 4;
#pragma unroll
    for (int i = 0; i < 4; ++i)
#pragma unroll
        for (int j = 0; j < 4; ++j) {
            int p = j * 16 + lrow;
#pragma unroll
            for (int r = 0; r < 4; ++r) {
                int l = w * 64 + i * 16 + rrow + r;
                float v = acc[i][j][r] + Dh * bf2f(xc[(base_s + l) * CONV_DIM + h * HEAD_DIM + p]);
                y[(base_s + l) * (long)HID + h * HEAD_DIM + p] = f2bf(v);
            }
        }
}

// ---------------- gate with silu(z), RMSNorm, bf16 out ----------------
__global__ __launch_bounds__(256) void k_norm(
    const unsigned short* __restrict__ y, const unsigned short* __restrict__ z,
    const float* __restrict__ norm_w, unsigned short* __restrict__ yb)
{
    int s = blockIdx.x;
    int t = threadIdx.x;
    const unsigned short* yrow = y + (long)s * HID;
    const unsigned short* zrow = z + (long)s * HID;
    float vals[16];
    float ss = 0.f;
#pragma unroll
    for (int i = 0; i < 16; ++i) {
        int j = t + i * 256;
        float yv = bf2f(yrow[j]);
        float zv = bf2f(zrow[j]);
        float g = yv * (zv / (1.f + __expf(-zv)));
        vals[i] = g;
        ss += g * g;
    }
#pragma unroll
    for (int off = 32; off > 0; off >>= 1) ss += __shfl_down(ss, off);
    __shared__ float wsum[4];
    int lane = t & 63, wid = t >> 6;
    if (lane == 0) wsum[wid] = ss;
    __syncthreads();
    float total = wsum[0] + wsum[1] + wsum[2] + wsum[3];
    float scale = rsqrtf(total / HID + 1e-5f);
#pragma unroll
    for (int i = 0; i < 16; ++i) {
        int j = t + i * 256;
        yb[(long)s * HID + j] = f2bf(vals[i] * scale * norm_w[j]);
    }
}

// ---------------- launch ----------------
extern "C" void kernel_launch(void* const* d_in, const int* in_sizes, int n_in,
                              void* d_out, int out_size, void* d_ws, size_t ws_size,
                              hipStream_t stream) {
    const float* x          = (const float*)d_in[0];
    const float* in_proj_w  = (const float*)d_in[1];
    const float* conv_w     = (const float*)d_in[2];
    const float* dt_bias    = (const float*)d_in[3];
    const float* A_log      = (const float*)d_in[4];
    const float* Dp         = (const float*)d_in[5];
    const float* norm_w     = (const float*)d_in[6];
    const float* out_proj_w = (const float*)d_in[7];
    char* ws = (char*)d_ws;

    // workspace layout (bytes) — total 131,600,384
    const size_t off_xb    = 0;                                        // bf16 x; later states fp32 (33.5MB, spans into wbin)
    const size_t off_wbin  = off_xb    + (size_t)SEQ * DIMIN * 2;      // bf16 in_proj padded; later wob
    const size_t off_xbcd  = off_wbin  + (size_t)WROWS * DIMIN * 2;    // bf16 xBC+dt; later y
    const size_t off_xc    = off_xbcd  + (size_t)SEQ * XBCD_N * 2;     // bf16 conv out; later yb
    const size_t off_dtraw = off_xc    + (size_t)SEQ * CONV_DIM * 2;
    const size_t off_dtv   = off_dtraw + (size_t)SEQ * 64 * 4;
    const size_t off_dAc   = off_dtv   + (size_t)SEQ * HEADS * 4;
    const size_t off_dAl   = off_dAc   + (size_t)SEQ * HEADS * 4;
    const size_t off_G     = off_dAl   + (size_t)NCHUNK * HEADS * 4;
    const size_t needed    = off_G     + (size_t)NCHUNK * CHUNK * CHUNK * 4;
    if (ws_size < needed) return;

    unsigned short* xb    = (unsigned short*)(ws + off_xb);
    unsigned short* wbin  = (unsigned short*)(ws + off_wbin);
    unsigned short* xbcd  = (unsigned short*)(ws + off_xbcd);
    unsigned short* xc    = (unsigned short*)(ws + off_xc);
    float* dtraw = (float*)(ws + off_dtraw);
    float* dtv   = (float*)(ws + off_dtv);
    float* dAc   = (float*)(ws + off_dAc);
    float* dAl   = (float*)(ws + off_dAl);
    float* G     = (float*)(ws + off_G);

    // states fp32 (33.5 MB) aliases xb+wbin head (both dead after merged GEMM1);
    // wob (16.7 MB at wbin base) only written after k_ssd_y consumes states.
    float* states      = (float*)(ws + off_xb);
    unsigned short* z  = (unsigned short*)d_out;   // z bf16 fills d_out exactly
    unsigned short* y  = xbcd;
    unsigned short* yb = xc;
    unsigned short* wob = wbin;

    { long n = (long)SEQ * DIMIN;
      k_convert<<<(unsigned)((n + 255) / 256), 256, 0, stream>>>(x, xb, n, n); }
    { long n = (long)WROWS * DIMIN, nsrc = (long)D_IN * DIMIN;
      k_convert<<<(unsigned)((n + 255) / 256), 256, 0, stream>>>(in_proj_w, wbin, n, nsrc); }
    // merged GEMM1: z + xBCdt + dtraw in one launch (2144 blocks)
    k_gemm_dual<<<dim3(WROWS / BN, SEQ / BM), 256, 0, stream>>>(
        xb, wbin, z, xbcd, dtraw, DIMIN);
    { long n = (long)SEQ * CONV_DIM;
      k_conv<<<(unsigned)((n + 255) / 256), 256, 0, stream>>>(xbcd, conv_w, xc); }
    k_dt<<<dim3(NCHUNK, HEADS), 256, 0, stream>>>(dtraw, dt_bias, A_log, dtv, dAc, dAl);
    k_G<<<dim3(NCHUNK, CHUNK), 256, 0, stream>>>(xc, G);
    k_states<<<dim3(NCHUNK, HEADS), 256, 0, stream>>>(xc, dtv, dAc, dAl, states);
    k_scan<<<(HEADS * HEAD_DIM * STATE) / 256, 256, 0, stream>>>(states, dAl);
    k_ssd_y<<<dim3(NCHUNK, HEADS), 256, 0, stream>>>(xc, G, dtv, dAc, states, Dp, y);
    k_norm<<<SEQ, 256, 0, stream>>>(y, z, norm_w, yb);
    { long n = (long)DIMIN * HID;
      k_convert<<<(unsigned)((n + 255) / 256), 256, 0, stream>>>(out_proj_w, wob, n, n); }
    k_gemm_f32<<<dim3(DIMIN / BN, SEQ / BM), 256, 0, stream>>>(
        yb, wob, (float*)d_out, HID, DIMIN);
}